// Round 2
// 4853.632 us; speedup vs baseline: 1.0664x; 1.0664x over previous
//
#include <hip/hip_runtime.h>
#include <math.h>

#define SEQ 2048
#define DIM 2048
#define NH 16
#define HD 128
#define CACHEB 408
#define RECENT 204
#define PEN 0.4f
#define QK_SCALE 0.08838834764831845f  // 1/sqrt(128)
#define BIGT 0x7fffffff

typedef unsigned short u16;
typedef __attribute__((ext_vector_type(8))) short bh8;   // 8 bf16 (4 VGPRs)
typedef __attribute__((ext_vector_type(4))) float f32x4; // MFMA acc

__device__ __forceinline__ u16 f2bf(float x) {           // RNE f32->bf16
    unsigned u = __float_as_uint(x);
    return (u16)((u + 0x7fffu + ((u >> 16) & 1u)) >> 16);
}
__device__ __forceinline__ void splitf(float x, u16& h, u16& l) {
    h = f2bf(x);
    float hf = __uint_as_float(((unsigned)h) << 16);
    l = f2bf(x - hf);
}

// ---------------- f32 -> (hi,lo) bf16 split, 4 elems/thread ---------------
__global__ __launch_bounds__(256)
void split_kernel(const float* __restrict__ src, u16* __restrict__ dh,
                  u16* __restrict__ dl, int n4)
{
    int i = blockIdx.x * 256 + threadIdx.x;
    if (i >= n4) return;
    float4 v = ((const float4*)src)[i];
    union { u16 s[4]; unsigned long long q; } oh, ol;
    splitf(v.x, oh.s[0], ol.s[0]); splitf(v.y, oh.s[1], ol.s[1]);
    splitf(v.z, oh.s[2], ol.s[2]); splitf(v.w, oh.s[3], ol.s[3]);
    ((unsigned long long*)dh)[i] = oh.q;
    ((unsigned long long*)dl)[i] = ol.q;
}

// ---------------- split-bf16 MFMA NT GEMM ---------------------------------
// C = scale * A(MxK) * B(NxK)^T with A ~ Ah+Al, B ~ Bh+Bl (bf16 pairs):
//   acc += Ah*Bh + Ah*Bl + Al*Bh      (~f32 accuracy, 3x MFMA)
// ASPLITF32/BSPLITF32: operand given as f32, split in-register.
// 128x128 tile, 4 waves, fragments direct from global.
// Fragment layouts (verified on-device, rounds 7-8):
//   A/B: lane=16*quad+r holds [r][quad*8 + 0..7]; C/D: col=lane&15, row=quad*4+reg
template<bool ASPLITF32, bool BSPLITF32, bool CAUSAL, bool TRUNCA>
__global__ __launch_bounds__(256, 2)
void mfma_nt(const void* __restrict__ Ah_, const void* __restrict__ Al_,
             const void* __restrict__ Bh_, const void* __restrict__ Bl_,
             float* __restrict__ Cp, int K, int lda, int ldb, int ldc,
             long aB, long bB, long cB, float scale)
{
    int m0 = blockIdx.y * 128, n0 = blockIdx.x * 128;
    if (CAUSAL && n0 > m0 + 127) return;

    const float* Af = (const float*)Ah_ + (size_t)blockIdx.z * aB;
    const u16*   Ah = (const u16*)Ah_   + (size_t)blockIdx.z * aB;
    const u16*   Al = (const u16*)Al_   + (size_t)blockIdx.z * aB;
    const float* Bf = (const float*)Bh_ + (size_t)blockIdx.z * bB;
    const u16*   Bh = (const u16*)Bh_   + (size_t)blockIdx.z * bB;
    const u16*   Bl = (const u16*)Bl_   + (size_t)blockIdx.z * bB;
    float* C = Cp + (size_t)blockIdx.z * cB;

    int lane = threadIdx.x & 63, wave = threadIdx.x >> 6;
    int wm = m0 + (wave >> 1) * 64, wn = n0 + (wave & 1) * 64;
    int fr = lane & 15, quad = lane >> 4;
    int kq = quad * 8;

    auto loadA = [&](int mt, int k, bh8& h, bh8& l) {
        int r = wm + mt * 16 + fr;
        if (ASPLITF32) {
            const float* p = Af + (size_t)r * lda + k + kq;
            float4 x = *(const float4*)p, y = *(const float4*)(p + 4);
            u16 hh, ll;
            splitf(x.x,hh,ll); h[0]=(short)hh; l[0]=(short)ll;
            splitf(x.y,hh,ll); h[1]=(short)hh; l[1]=(short)ll;
            splitf(x.z,hh,ll); h[2]=(short)hh; l[2]=(short)ll;
            splitf(x.w,hh,ll); h[3]=(short)hh; l[3]=(short)ll;
            splitf(y.x,hh,ll); h[4]=(short)hh; l[4]=(short)ll;
            splitf(y.y,hh,ll); h[5]=(short)hh; l[5]=(short)ll;
            splitf(y.z,hh,ll); h[6]=(short)hh; l[6]=(short)ll;
            splitf(y.w,hh,ll); h[7]=(short)hh; l[7]=(short)ll;
        } else {
            h = *(const bh8*)(Ah + (size_t)r * lda + k + kq);
            l = *(const bh8*)(Al + (size_t)r * lda + k + kq);
        }
    };
    auto loadB = [&](int nt, int k, bh8& h, bh8& l) {
        int r = wn + nt * 16 + fr;
        if (BSPLITF32) {
            const float* p = Bf + (size_t)r * ldb + k + kq;
            float4 x = *(const float4*)p, y = *(const float4*)(p + 4);
            u16 hh, ll;
            splitf(x.x,hh,ll); h[0]=(short)hh; l[0]=(short)ll;
            splitf(x.y,hh,ll); h[1]=(short)hh; l[1]=(short)ll;
            splitf(x.z,hh,ll); h[2]=(short)hh; l[2]=(short)ll;
            splitf(x.w,hh,ll); h[3]=(short)hh; l[3]=(short)ll;
            splitf(y.x,hh,ll); h[4]=(short)hh; l[4]=(short)ll;
            splitf(y.y,hh,ll); h[5]=(short)hh; l[5]=(short)ll;
            splitf(y.z,hh,ll); h[6]=(short)hh; l[6]=(short)ll;
            splitf(y.w,hh,ll); h[7]=(short)hh; l[7]=(short)ll;
        } else {
            h = *(const bh8*)(Bh + (size_t)r * ldb + k + kq);
            l = *(const bh8*)(Bl + (size_t)r * ldb + k + kq);
        }
    };

    f32x4 acc[4][4] = {};
    int Keff = TRUNCA ? min(K, m0 + 128) : K;

    for (int k0 = 0; k0 < Keff; k0 += 32) {
        bh8 ah[4], al[4], bh[4], bl[4];
        #pragma unroll
        for (int i = 0; i < 4; i++) { loadA(i, k0, ah[i], al[i]); loadB(i, k0, bh[i], bl[i]); }
        #pragma unroll
        for (int mt = 0; mt < 4; mt++)
            #pragma unroll
            for (int nt = 0; nt < 4; nt++) {
                acc[mt][nt] = __builtin_amdgcn_mfma_f32_16x16x32_bf16(ah[mt], bh[nt], acc[mt][nt], 0, 0, 0);
                acc[mt][nt] = __builtin_amdgcn_mfma_f32_16x16x32_bf16(ah[mt], bl[nt], acc[mt][nt], 0, 0, 0);
                acc[mt][nt] = __builtin_amdgcn_mfma_f32_16x16x32_bf16(al[mt], bh[nt], acc[mt][nt], 0, 0, 0);
            }
    }

    #pragma unroll
    for (int mt = 0; mt < 4; mt++)
        #pragma unroll
        for (int r = 0; r < 4; r++) {
            int row = wm + mt * 16 + quad * 4 + r;
            #pragma unroll
            for (int nt = 0; nt < 4; nt++) {
                int col = wn + nt * 16 + fr;
                C[(size_t)row * ldc + col] = acc[mt][nt][r] * scale;
            }
        }
}

// ---------------- RoPE in place on Q and K (f32) ---------------------------
__global__ __launch_bounds__(256)
void rope_qk(float* __restrict__ Q, float* __restrict__ K, const int* __restrict__ pos_ids)
{
    int s = blockIdx.x;
    int i = threadIdx.x & 63;
    int h = blockIdx.y * 4 + (threadIdx.x >> 6);
    double p = (double)pos_ids[s];
    double invf = exp(-((double)(2 * i) / (double)HD) * 9.210340371976184); // ln(10000)
    double ang = p * invf;
    float c = (float)cos(ang), sn = (float)sin(ang);
    size_t b = (size_t)s * DIM + (size_t)h * HD;
    float q0 = Q[b + i], q1 = Q[b + i + 64];
    Q[b + i]      = q0 * c - q1 * sn;
    Q[b + i + 64] = q1 * c + q0 * sn;
    float k0 = K[b + i], k1 = K[b + i + 64];
    K[b + i]      = k0 * c - k1 * sn;
    K[b + i + 64] = k1 * c + k0 * sn;
}

// ---------------- V(f32) -> Vt hi/lo bf16 [h][hd][s] -----------------------
__global__ __launch_bounds__(1024)
void transpose_v(const float* __restrict__ V, u16* __restrict__ Vth, u16* __restrict__ Vtl)
{
    __shared__ float tile[32][33];
    int h = blockIdx.z;
    int j0 = blockIdx.x * 32, d0 = blockIdx.y * 32;
    int tx = threadIdx.x, ty = threadIdx.y;
    tile[ty][tx] = V[(size_t)(j0 + ty) * DIM + (size_t)h * HD + d0 + tx];
    __syncthreads();
    u16 hh, ll; splitf(tile[tx][ty], hh, ll);
    size_t idx = (size_t)h * HD * SEQ + (size_t)(d0 + ty) * SEQ + j0 + tx;
    Vth[idx] = hh; Vtl[idx] = ll;
}

// ---------------- row softmax (causal) in place on Sc ---------------------
__global__ __launch_bounds__(256)
void softmax_rows(float* __restrict__ Sc)
{
    int r = blockIdx.x, h = blockIdx.y;
    float* row = Sc + ((size_t)h * SEQ + r) * SEQ;
    int n = r + 1;
    __shared__ float red[256];
    int tid = threadIdx.x;
    float mx = -INFINITY;
    for (int j = tid; j < n; j += 256) mx = fmaxf(mx, row[j]);
    red[tid] = mx; __syncthreads();
    for (int s = 128; s; s >>= 1) { if (tid < s) red[tid] = fmaxf(red[tid], red[tid + s]); __syncthreads(); }
    mx = red[0]; __syncthreads();
    float sum = 0.f;
    for (int j = tid; j < n; j += 256) { float e = expf(row[j] - mx); row[j] = e; sum += e; }
    red[tid] = sum; __syncthreads();
    for (int s = 128; s; s >>= 1) { if (tid < s) red[tid] += red[tid + s]; __syncthreads(); }
    float inv = 1.f / red[0];
    for (int j = tid; j < n; j += 256) row[j] *= inv;
    for (int j = n + tid; j < SEQ; j += 256) row[j] = 0.f;
}

// ---------------- parallel warmup: select0[h][c] = sum_t PEN^(407-t)*Sc[t][c]
__global__ __launch_bounds__(256)
void warmup_select(const float* __restrict__ Sc, float* __restrict__ sel0)
{
    int h = blockIdx.y;
    int col = blockIdx.x * 256 + threadIdx.x;
    const float* S = Sc + (size_t)h * SEQ * SEQ + col;
    float s = 0.f;
    #pragma unroll 4
    for (int t = 0; t < CACHEB; t++) s = PEN * s + S[(size_t)t * SEQ];
    sel0[h * SEQ + col] = s;
}

// ---------------- DPP cross-lane helpers ----------------------------------
#define DPP_SUMSTEP(x, ctrl) \
    x += __int_as_float(__builtin_amdgcn_update_dpp(0, __float_as_int(x), ctrl, 0xF, 0xF, true))
#define DPP_SUMBC(x, ctrl) \
    x += __int_as_float(__builtin_amdgcn_update_dpp(0, __float_as_int(x), ctrl, 0xF, 0xF, false))
#define DPP_MINF(x, ctrl) \
    x = fminf(x, __int_as_float(__builtin_amdgcn_update_dpp(__float_as_int(x), __float_as_int(x), ctrl, 0xF, 0xF, false)))
#define DPP_MINU(x, ctrl) \
    { unsigned t_ = (unsigned)__builtin_amdgcn_update_dpp((int)(x), (int)(x), ctrl, 0xF, 0xF, false); x = t_ < x ? t_ : x; }

__device__ __forceinline__ float wave_sum64(float x) {
    DPP_SUMSTEP(x, 0x111); DPP_SUMSTEP(x, 0x112);
    DPP_SUMSTEP(x, 0x114); DPP_SUMSTEP(x, 0x118);
    DPP_SUMBC(x, 0x142);   DPP_SUMBC(x, 0x143);
    return __int_as_float(__builtin_amdgcn_readlane(__float_as_int(x), 63));
}
__device__ __forceinline__ float wave_min64f(float x) {
    DPP_MINF(x, 0x111); DPP_MINF(x, 0x112);
    DPP_MINF(x, 0x114); DPP_MINF(x, 0x118);
    DPP_MINF(x, 0x142); DPP_MINF(x, 0x143);
    return __int_as_float(__builtin_amdgcn_readlane(__float_as_int(x), 63));
}
__device__ __forceinline__ unsigned wave_min64u(unsigned x) {
    DPP_MINU(x, 0x111); DPP_MINU(x, 0x112);
    DPP_MINU(x, 0x114); DPP_MINU(x, 0x118);
    DPP_MINU(x, 0x142); DPP_MINU(x, 0x143);
    return (unsigned)__builtin_amdgcn_readlane((int)x, 63);
}

// ---------------- H2O scan: single wave, register-prefetch pipeline --------
// One 64-lane wave per head. Rows are prefetched 4 steps ahead directly from
// global into 4 statically-indexed register buffers (no LDS ring, no second
// wave, no volatile polls / fences / sleeps). Per-lane math and reduction
// order are bit-identical to the previous producer/consumer version.
__global__ __launch_bounds__(64, 1)
void h2o_scan5(const float* __restrict__ Sc, const float* __restrict__ sel0,
               int* __restrict__ evict)
{
    __shared__ int et[SEQ];               // 8 KB

    int h = blockIdx.x;
    int l = threadIdx.x;                  // 0..63, one wave
    const float* Sh = Sc + (size_t)h * SEQ * SEQ;
    const float* gb = Sh + (l << 2);

    #pragma unroll
    for (int s = 0; s < SEQ / 64; s++) et[s * 64 + l] = BIGT;

    float sel[32];
    const float* s0 = sel0 + h * SEQ + l * 4;
    #pragma unroll
    for (int i = 0; i < 8; i++) {
        float4 v = *(const float4*)(s0 + i * 256);
        sel[i*4+0]=v.x; sel[i*4+1]=v.y; sel[i*4+2]=v.z; sel[i*4+3]=v.w;
    }

    unsigned mask = 0xffffffffu;
    unsigned candBits = 0;
    #pragma unroll
    for (int k = 0; k < 32; k++) {
        int p = ((k >> 2) << 8) + l * 4 + (k & 3);
        if (p <= CACHEB - RECENT) candBits |= 1u << k;
    }

    float4 bA[8], bB[8], bC[8], bD[8];
    auto loadrow = [&](int r, float4 (&b)[8]) {
        const float* g = gb + (size_t)r * SEQ;
        #pragma unroll
        for (int i = 0; i < 8; i++) b[i] = *(const float4*)(g + i * 256);
    };
    loadrow(CACHEB + 0, bA);
    loadrow(CACHEB + 1, bB);
    loadrow(CACHEB + 2, bC);
    loadrow(CACHEB + 3, bD);

    auto step = [&](int t, float4 (&cur)[8]) {
        float m[32];
        float p0 = 0.f, p1 = 0.f, p2 = 0.f, p3 = 0.f;
        #pragma unroll
        for (int i = 0; i < 8; i++) {
            float4 b = cur[i];
            m[i*4+0] = (mask & (1u << (i*4+0))) ? b.x : 0.f;
            m[i*4+1] = (mask & (1u << (i*4+1))) ? b.y : 0.f;
            m[i*4+2] = (mask & (1u << (i*4+2))) ? b.z : 0.f;
            m[i*4+3] = (mask & (1u << (i*4+3))) ? b.w : 0.f;
            p0 += m[i*4+0]; p1 += m[i*4+1]; p2 += m[i*4+2]; p3 += m[i*4+3];
        }
        #pragma unroll
        for (int k = 0; k < 32; k++) sel[k] *= PEN;
        float part = wave_sum64((p0 + p1) + (p2 + p3));
        float inv = 1.f / part;

        unsigned cm = mask & candBits;
        float cv[32];
        #pragma unroll
        for (int k = 0; k < 32; k++) {
            float s2 = fmaf(m[k], inv, sel[k]);
            sel[k] = s2;
            cv[k] = ((cm >> k) & 1u) ? s2 : INFINITY;
        }
        float m16[16];
        #pragma unroll
        for (int k = 0; k < 16; k++) m16[k] = fminf(cv[k], cv[k + 16]);
        float m8[8];
        #pragma unroll
        for (int k = 0; k < 8; k++) m8[k] = fminf(m16[k], m16[k + 8]);
        float m4[4];
        #pragma unroll
        for (int k = 0; k < 4; k++) m4[k] = fminf(m8[k], m8[k + 4]);
        float lmin = fminf(fminf(m4[0], m4[1]), fminf(m4[2], m4[3]));
        float gm = wave_min64f(lmin);

        unsigned mb = 0;
        #pragma unroll
        for (int k = 0; k < 32; k++) mb |= (cv[k] == gm) ? (1u << k) : 0u;
        int mk = __ffs(mb) - 1;
        unsigned lpos = mb ? (unsigned)(((mk >> 2) << 8) + l * 4 + (mk & 3))
                           : 0xffffffffu;
        unsigned bpos = wave_min64u(lpos);

        int ke = (((bpos >> 8) << 2) | (bpos & 3));
        if ((((int)bpos >> 2) & 63) == l) mask &= ~(1u << ke);
        if (l == 0) et[bpos] = t;

        int newc = t + 1 - RECENT;
        if (((newc >> 2) & 63) == l) candBits |= 1u << (((newc >> 8) << 2) | (newc & 3));
    };

    int t = CACHEB;
    // main loop: process t..t+3 from bA..bD, prefetch t+4..t+7 (row 2047 is
    // in-bounds and merely unused)
    for (; t + 7 <= SEQ - 1; t += 4) {
        step(t + 0, bA); loadrow(t + 4, bA);
        step(t + 1, bB); loadrow(t + 5, bB);
        step(t + 2, bC); loadrow(t + 6, bC);
        step(t + 3, bD); loadrow(t + 7, bD);
    }
    // tail (t = 2044, 2045, 2046 for SEQ=2048/CACHEB=408)
    if (t <= SEQ - 2) { step(t, bA); t++; }
    if (t <= SEQ - 2) { step(t, bB); t++; }
    if (t <= SEQ - 2) { step(t, bC); t++; }

    #pragma unroll
    for (int s = 0; s < SEQ / 64; s++)
        evict[h * SEQ + s * 64 + l] = et[s * 64 + l];
}

// ---------------- apply mask + renormalize rows >= CACHEB in place --------
__global__ __launch_bounds__(256)
void mask_renorm(float* __restrict__ Sc, const int* __restrict__ evict)
{
    int r = CACHEB + blockIdx.x;
    int h = blockIdx.y;
    float* row = Sc + ((size_t)h * SEQ + r) * SEQ;
    const int* et = evict + h * SEQ;
    int tid = threadIdx.x;
    __shared__ float red[256];
    float v[8]; float sum = 0.f;
    #pragma unroll
    for (int s = 0; s < 8; s++) {
        int c = s * 256 + tid;
        float x = row[c];
        v[s] = (et[c] >= r) ? x : 0.f;
        sum += v[s];
    }
    red[tid] = sum; __syncthreads();
    for (int s = 128; s; s >>= 1) { if (tid < s) red[tid] += red[tid + s]; __syncthreads(); }
    float inv = 1.f / red[0];
    #pragma unroll
    for (int s = 0; s < 8; s++) row[s * 256 + tid] = v[s] * inv;
}

extern "C" void kernel_launch(void* const* d_in, const int* in_sizes, int n_in,
                              void* d_out, int out_size, void* d_ws, size_t ws_size,
                              hipStream_t stream)
{
    const float* hidden = (const float*)d_in[0];
    const int*   pos    = (const int*)d_in[2];
    const float* wq     = (const float*)d_in[3];
    const float* wk     = (const float*)d_in[4];
    const float* wv     = (const float*)d_in[5];
    const float* wo     = (const float*)d_in[6];
    float* out = (float*)d_out;

    float* ws = (float*)d_ws;
    const size_t SD = (size_t)SEQ * DIM;           // 4M elems
    float* Q    = ws;                              // f32, 16 MB
    float* K    = ws + SD;                         // f32, 16 MB
    float* V    = ws + 2 * SD;                     // f32; becomes O after transpose
    float* O    = V;
    u16*   Vth  = (u16*)(ws + 3 * SD);             // bf16-hi Vt (8 MB)
    u16*   Vtl  = Vth + SD;                        // bf16-lo Vt (8 MB)
    float* sel0 = ws + 4 * SD;                     // NH*SEQ floats
    int*   evct = (int*)(ws + 4 * SD + (size_t)NH * SEQ);
    float* Sc   = ws + 4 * SD + 2 * (size_t)NH * SEQ;   // g * SEQ*SEQ floats

    // staging (hi/lo splits) in the not-yet-used Sc region: 4 arrays x SD u16
    u16* hh = (u16*)Sc;        // hidden hi
    u16* hl = hh + SD;         // hidden lo
    u16* wh = hl + SD;         // current weight hi (reused per weight)
    u16* wl = wh + SD;         // current weight lo

    const size_t fixedB   = (4 * SD + 2 * (size_t)NH * SEQ) * sizeof(float);
    const size_t perHeadB = (size_t)SEQ * SEQ * sizeof(float);
    int g = NH;
    while (g > 1 && fixedB + (size_t)g * perHeadB > ws_size) g >>= 1;

    const int N4 = (int)(SD / 4);
    const int CB = (N4 + 255) / 256;

    // 0-1. split + projections (weights staged sequentially)
    split_kernel<<<CB, 256, 0, stream>>>(hidden, hh, hl, N4);
    split_kernel<<<CB, 256, 0, stream>>>(wq, wh, wl, N4);
    mfma_nt<false,false,false,false><<<dim3(16,16,1), 256, 0, stream>>>(
        hh, hl, wh, wl, Q, DIM, DIM, DIM, DIM, 0, 0, 0, 1.f);
    split_kernel<<<CB, 256, 0, stream>>>(wk, wh, wl, N4);
    mfma_nt<false,false,false,false><<<dim3(16,16,1), 256, 0, stream>>>(
        hh, hl, wh, wl, K, DIM, DIM, DIM, DIM, 0, 0, 0, 1.f);
    split_kernel<<<CB, 256, 0, stream>>>(wv, wh, wl, N4);
    mfma_nt<false,false,false,false><<<dim3(16,16,1), 256, 0, stream>>>(
        hh, hl, wh, wl, V, DIM, DIM, DIM, DIM, 0, 0, 0, 1.f);

    // 2. RoPE on Q, K (f32, in place)
    rope_qk<<<dim3(SEQ, NH / 4), 256, 0, stream>>>(Q, K, pos);

    // 3. V -> Vt hi/lo (V storage then becomes O)
    transpose_v<<<dim3(SEQ / 32, HD / 32, NH), dim3(32, 32), 0, stream>>>(V, Vth, Vtl);

    // 4-8 per head-group
    for (int h0 = 0; h0 < NH; h0 += g) {
        int gc = min(g, NH - h0);
        // QK logits: f32 Q,K split in-register, causal tiles, f32 out
        mfma_nt<true,true,true,false><<<dim3(16,16,gc), 256, 0, stream>>>(
            Q + (size_t)h0 * HD, nullptr, K + (size_t)h0 * HD, nullptr, Sc, HD,
            DIM, DIM, SEQ, HD, HD, (long)SEQ * SEQ, QK_SCALE);
        softmax_rows<<<dim3(SEQ, gc), 256, 0, stream>>>(Sc);
        warmup_select<<<dim3(SEQ / 256, gc), 256, 0, stream>>>(Sc, sel0);
        h2o_scan5<<<dim3(gc), 64, 0, stream>>>(Sc, sel0, evct);
        mask_renorm<<<dim3(SEQ - CACHEB, gc), 256, 0, stream>>>(Sc, evct);
        // PV: probs f32 split in-register (K-truncated), Vt pre-split, f32 out
        mfma_nt<true,false,false,true><<<dim3(1,16,gc), 256, 0, stream>>>(
            Sc, nullptr, Vth + (size_t)h0 * HD * SEQ, Vtl + (size_t)h0 * HD * SEQ,
            O + (size_t)h0 * HD, SEQ, SEQ, SEQ, DIM,
            (long)SEQ * SEQ, (long)HD * SEQ, HD, 1.f);
    }

    // 9. final projection: out = O @ wo^T (O split in-register, wo pre-split)
    split_kernel<<<CB, 256, 0, stream>>>(wo, wh, wl, N4);
    mfma_nt<true,false,false,false><<<dim3(16,16,1), 256, 0, stream>>>(
        O, nullptr, wh, wl, out, DIM, DIM, DIM, DIM, 0, 0, 0, 1.f);
}

// Round 3
// 4526.207 us; speedup vs baseline: 1.1435x; 1.0723x over previous
//
#include <hip/hip_runtime.h>
#include <math.h>

#define SEQ 2048
#define DIM 2048
#define NH 16
#define HD 128
#define CACHEB 408
#define RECENT 204
#define PEN 0.4f
#define QK_SCALE 0.08838834764831845f  // 1/sqrt(128)
#define BIGT 0x7fffffff

typedef unsigned short u16;
typedef unsigned long long u64;
typedef __attribute__((ext_vector_type(8))) short bh8;   // 8 bf16 (4 VGPRs)
typedef __attribute__((ext_vector_type(4))) float f32x4; // MFMA acc

__device__ __forceinline__ u16 f2bf(float x) {           // RNE f32->bf16
    unsigned u = __float_as_uint(x);
    return (u16)((u + 0x7fffu + ((u >> 16) & 1u)) >> 16);
}
__device__ __forceinline__ void splitf(float x, u16& h, u16& l) {
    h = f2bf(x);
    float hf = __uint_as_float(((unsigned)h) << 16);
    l = f2bf(x - hf);
}

// ---------------- f32 -> (hi,lo) bf16 split, 4 elems/thread ---------------
__global__ __launch_bounds__(256)
void split_kernel(const float* __restrict__ src, u16* __restrict__ dh,
                  u16* __restrict__ dl, int n4)
{
    int i = blockIdx.x * 256 + threadIdx.x;
    if (i >= n4) return;
    float4 v = ((const float4*)src)[i];
    union { u16 s[4]; unsigned long long q; } oh, ol;
    splitf(v.x, oh.s[0], ol.s[0]); splitf(v.y, oh.s[1], ol.s[1]);
    splitf(v.z, oh.s[2], ol.s[2]); splitf(v.w, oh.s[3], ol.s[3]);
    ((unsigned long long*)dh)[i] = oh.q;
    ((unsigned long long*)dl)[i] = ol.q;
}

// ---------------- split-bf16 MFMA NT GEMM ---------------------------------
// C = scale * A(MxK) * B(NxK)^T with A ~ Ah+Al, B ~ Bh+Bl (bf16 pairs):
//   acc += Ah*Bh + Ah*Bl + Al*Bh      (~f32 accuracy, 3x MFMA)
// ASPLITF32/BSPLITF32: operand given as f32, split in-register.
// 128x128 tile, 4 waves, fragments direct from global.
// Fragment layouts (verified on-device, rounds 7-8):
//   A/B: lane=16*quad+r holds [r][quad*8 + 0..7]; C/D: col=lane&15, row=quad*4+reg
template<bool ASPLITF32, bool BSPLITF32, bool CAUSAL, bool TRUNCA>
__global__ __launch_bounds__(256, 2)
void mfma_nt(const void* __restrict__ Ah_, const void* __restrict__ Al_,
             const void* __restrict__ Bh_, const void* __restrict__ Bl_,
             float* __restrict__ Cp, int K, int lda, int ldb, int ldc,
             long aB, long bB, long cB, float scale)
{
    int m0 = blockIdx.y * 128, n0 = blockIdx.x * 128;
    if (CAUSAL && n0 > m0 + 127) return;

    const float* Af = (const float*)Ah_ + (size_t)blockIdx.z * aB;
    const u16*   Ah = (const u16*)Ah_   + (size_t)blockIdx.z * aB;
    const u16*   Al = (const u16*)Al_   + (size_t)blockIdx.z * aB;
    const float* Bf = (const float*)Bh_ + (size_t)blockIdx.z * bB;
    const u16*   Bh = (const u16*)Bh_   + (size_t)blockIdx.z * bB;
    const u16*   Bl = (const u16*)Bl_   + (size_t)blockIdx.z * bB;
    float* C = Cp + (size_t)blockIdx.z * cB;

    int lane = threadIdx.x & 63, wave = threadIdx.x >> 6;
    int wm = m0 + (wave >> 1) * 64, wn = n0 + (wave & 1) * 64;
    int fr = lane & 15, quad = lane >> 4;
    int kq = quad * 8;

    auto loadA = [&](int mt, int k, bh8& h, bh8& l) {
        int r = wm + mt * 16 + fr;
        if (ASPLITF32) {
            const float* p = Af + (size_t)r * lda + k + kq;
            float4 x = *(const float4*)p, y = *(const float4*)(p + 4);
            u16 hh, ll;
            splitf(x.x,hh,ll); h[0]=(short)hh; l[0]=(short)ll;
            splitf(x.y,hh,ll); h[1]=(short)hh; l[1]=(short)ll;
            splitf(x.z,hh,ll); h[2]=(short)hh; l[2]=(short)ll;
            splitf(x.w,hh,ll); h[3]=(short)hh; l[3]=(short)ll;
            splitf(y.x,hh,ll); h[4]=(short)hh; l[4]=(short)ll;
            splitf(y.y,hh,ll); h[5]=(short)hh; l[5]=(short)ll;
            splitf(y.z,hh,ll); h[6]=(short)hh; l[6]=(short)ll;
            splitf(y.w,hh,ll); h[7]=(short)hh; l[7]=(short)ll;
        } else {
            h = *(const bh8*)(Ah + (size_t)r * lda + k + kq);
            l = *(const bh8*)(Al + (size_t)r * lda + k + kq);
        }
    };
    auto loadB = [&](int nt, int k, bh8& h, bh8& l) {
        int r = wn + nt * 16 + fr;
        if (BSPLITF32) {
            const float* p = Bf + (size_t)r * ldb + k + kq;
            float4 x = *(const float4*)p, y = *(const float4*)(p + 4);
            u16 hh, ll;
            splitf(x.x,hh,ll); h[0]=(short)hh; l[0]=(short)ll;
            splitf(x.y,hh,ll); h[1]=(short)hh; l[1]=(short)ll;
            splitf(x.z,hh,ll); h[2]=(short)hh; l[2]=(short)ll;
            splitf(x.w,hh,ll); h[3]=(short)hh; l[3]=(short)ll;
            splitf(y.x,hh,ll); h[4]=(short)hh; l[4]=(short)ll;
            splitf(y.y,hh,ll); h[5]=(short)hh; l[5]=(short)ll;
            splitf(y.z,hh,ll); h[6]=(short)hh; l[6]=(short)ll;
            splitf(y.w,hh,ll); h[7]=(short)hh; l[7]=(short)ll;
        } else {
            h = *(const bh8*)(Bh + (size_t)r * ldb + k + kq);
            l = *(const bh8*)(Bl + (size_t)r * ldb + k + kq);
        }
    };

    f32x4 acc[4][4] = {};
    int Keff = TRUNCA ? min(K, m0 + 128) : K;

    for (int k0 = 0; k0 < Keff; k0 += 32) {
        bh8 ah[4], al[4], bh[4], bl[4];
        #pragma unroll
        for (int i = 0; i < 4; i++) { loadA(i, k0, ah[i], al[i]); loadB(i, k0, bh[i], bl[i]); }
        #pragma unroll
        for (int mt = 0; mt < 4; mt++)
            #pragma unroll
            for (int nt = 0; nt < 4; nt++) {
                acc[mt][nt] = __builtin_amdgcn_mfma_f32_16x16x32_bf16(ah[mt], bh[nt], acc[mt][nt], 0, 0, 0);
                acc[mt][nt] = __builtin_amdgcn_mfma_f32_16x16x32_bf16(ah[mt], bl[nt], acc[mt][nt], 0, 0, 0);
                acc[mt][nt] = __builtin_amdgcn_mfma_f32_16x16x32_bf16(al[mt], bh[nt], acc[mt][nt], 0, 0, 0);
            }
    }

    #pragma unroll
    for (int mt = 0; mt < 4; mt++)
        #pragma unroll
        for (int r = 0; r < 4; r++) {
            int row = wm + mt * 16 + quad * 4 + r;
            #pragma unroll
            for (int nt = 0; nt < 4; nt++) {
                int col = wn + nt * 16 + fr;
                C[(size_t)row * ldc + col] = acc[mt][nt][r] * scale;
            }
        }
}

// ---------------- RoPE in place on Q and K (f32) ---------------------------
__global__ __launch_bounds__(256)
void rope_qk(float* __restrict__ Q, float* __restrict__ K, const int* __restrict__ pos_ids)
{
    int s = blockIdx.x;
    int i = threadIdx.x & 63;
    int h = blockIdx.y * 4 + (threadIdx.x >> 6);
    double p = (double)pos_ids[s];
    double invf = exp(-((double)(2 * i) / (double)HD) * 9.210340371976184); // ln(10000)
    double ang = p * invf;
    float c = (float)cos(ang), sn = (float)sin(ang);
    size_t b = (size_t)s * DIM + (size_t)h * HD;
    float q0 = Q[b + i], q1 = Q[b + i + 64];
    Q[b + i]      = q0 * c - q1 * sn;
    Q[b + i + 64] = q1 * c + q0 * sn;
    float k0 = K[b + i], k1 = K[b + i + 64];
    K[b + i]      = k0 * c - k1 * sn;
    K[b + i + 64] = k1 * c + k0 * sn;
}

// ---------------- V(f32) -> Vt hi/lo bf16 [h][hd][s] -----------------------
__global__ __launch_bounds__(1024)
void transpose_v(const float* __restrict__ V, u16* __restrict__ Vth, u16* __restrict__ Vtl)
{
    __shared__ float tile[32][33];
    int h = blockIdx.z;
    int j0 = blockIdx.x * 32, d0 = blockIdx.y * 32;
    int tx = threadIdx.x, ty = threadIdx.y;
    tile[ty][tx] = V[(size_t)(j0 + ty) * DIM + (size_t)h * HD + d0 + tx];
    __syncthreads();
    u16 hh, ll; splitf(tile[tx][ty], hh, ll);
    size_t idx = (size_t)h * HD * SEQ + (size_t)(d0 + ty) * SEQ + j0 + tx;
    Vth[idx] = hh; Vtl[idx] = ll;
}

// ---------------- row softmax (causal) in place on Sc ---------------------
__global__ __launch_bounds__(256)
void softmax_rows(float* __restrict__ Sc)
{
    int r = blockIdx.x, h = blockIdx.y;
    float* row = Sc + ((size_t)h * SEQ + r) * SEQ;
    int n = r + 1;
    __shared__ float red[256];
    int tid = threadIdx.x;
    float mx = -INFINITY;
    for (int j = tid; j < n; j += 256) mx = fmaxf(mx, row[j]);
    red[tid] = mx; __syncthreads();
    for (int s = 128; s; s >>= 1) { if (tid < s) red[tid] = fmaxf(red[tid], red[tid + s]); __syncthreads(); }
    mx = red[0]; __syncthreads();
    float sum = 0.f;
    for (int j = tid; j < n; j += 256) { float e = expf(row[j] - mx); row[j] = e; sum += e; }
    red[tid] = sum; __syncthreads();
    for (int s = 128; s; s >>= 1) { if (tid < s) red[tid] += red[tid + s]; __syncthreads(); }
    float inv = 1.f / red[0];
    for (int j = tid; j < n; j += 256) row[j] *= inv;
    for (int j = n + tid; j < SEQ; j += 256) row[j] = 0.f;
}

// ---------------- parallel warmup: select0[h][c] = sum_t PEN^(407-t)*Sc[t][c]
__global__ __launch_bounds__(256)
void warmup_select(const float* __restrict__ Sc, float* __restrict__ sel0)
{
    int h = blockIdx.y;
    int col = blockIdx.x * 256 + threadIdx.x;
    const float* S = Sc + (size_t)h * SEQ * SEQ + col;
    float s = 0.f;
    #pragma unroll 4
    for (int t = 0; t < CACHEB; t++) s = PEN * s + S[(size_t)t * SEQ];
    sel0[h * SEQ + col] = s;
}

// ---------------- DPP cross-lane helpers ----------------------------------
#define DPP_SUMSTEP(x, ctrl) \
    x += __int_as_float(__builtin_amdgcn_update_dpp(0, __float_as_int(x), ctrl, 0xF, 0xF, true))
#define DPP_SUMBC(x, ctrl) \
    x += __int_as_float(__builtin_amdgcn_update_dpp(0, __float_as_int(x), ctrl, 0xF, 0xF, false))

__device__ __forceinline__ float wave_sum64(float x) {
    DPP_SUMSTEP(x, 0x111); DPP_SUMSTEP(x, 0x112);
    DPP_SUMSTEP(x, 0x114); DPP_SUMSTEP(x, 0x118);
    DPP_SUMBC(x, 0x142);   DPP_SUMBC(x, 0x143);
    return __int_as_float(__builtin_amdgcn_readlane(__float_as_int(x), 63));
}

// 64-bit (value,pos) key min-reduction across the wave. Same shr/bcast
// pattern as the verified f32/u32 reducers; min is idempotent so
// bound_ctrl=false lanes (old value) are harmless.
#define DPP_MIN_U64(x, ctrl) do { \
    unsigned lo_ = (unsigned)(x), hi_ = (unsigned)((x) >> 32); \
    unsigned nlo_ = (unsigned)__builtin_amdgcn_update_dpp((int)lo_, (int)lo_, ctrl, 0xF, 0xF, false); \
    unsigned nhi_ = (unsigned)__builtin_amdgcn_update_dpp((int)hi_, (int)hi_, ctrl, 0xF, 0xF, false); \
    u64 o_ = ((u64)nhi_ << 32) | nlo_; \
    if (o_ < (x)) (x) = o_; \
} while (0)

__device__ __forceinline__ u64 wave_min64_u64(u64 x) {
    DPP_MIN_U64(x, 0x111); DPP_MIN_U64(x, 0x112);
    DPP_MIN_U64(x, 0x114); DPP_MIN_U64(x, 0x118);
    DPP_MIN_U64(x, 0x142); DPP_MIN_U64(x, 0x143);
    unsigned rlo = (unsigned)__builtin_amdgcn_readlane((int)(unsigned)x, 63);
    unsigned rhi = (unsigned)__builtin_amdgcn_readlane((int)(unsigned)(x >> 32), 63);
    return ((u64)rhi << 32) | rlo;
}

// sign-extend bit k of msk to all 32 bits (0 or 0xFFFFFFFF); compiles to v_bfe_i32
#define SEXT_BIT(msk, k) ((unsigned)(((int)((msk) << (31 - (k)))) >> 31))

// ---------------- H2O scan: single wave, register prefetch, u64-key argmin -
// Value path (masked row, sum order, sel*=PEN, exact 1/part, fma) is
// op-identical to the previous passing version. Argmin is extracted via
// u64 keys (value_bits<<32 | pos): min over keys == (min value, tie -> min
// position) == reference argmin semantics, replacing the float min-tree +
// 32x equality-match + ffs + second wave reduction (the VCC-serialized part).
__global__ __launch_bounds__(64, 1)
void h2o_scan6(const float* __restrict__ Sc, const float* __restrict__ sel0,
               int* __restrict__ evict)
{
    __shared__ int et[SEQ];               // 8 KB

    int h = blockIdx.x;
    int l = threadIdx.x;                  // 0..63, one wave
    const float* Sh = Sc + (size_t)h * SEQ * SEQ;
    const float* gb = Sh + (l << 2);

    #pragma unroll
    for (int s = 0; s < SEQ / 64; s++) et[s * 64 + l] = BIGT;

    float sel[32];
    const float* s0 = sel0 + h * SEQ + l * 4;
    #pragma unroll
    for (int i = 0; i < 8; i++) {
        float4 v = *(const float4*)(s0 + i * 256);
        sel[i*4+0]=v.x; sel[i*4+1]=v.y; sel[i*4+2]=v.z; sel[i*4+3]=v.w;
    }

    unsigned mask = 0xffffffffu;
    unsigned candBits = 0;
    unsigned lo32[32];                    // exact position of (k, lane)
    #pragma unroll
    for (int k = 0; k < 32; k++) {
        int p = ((k >> 2) << 8) + l * 4 + (k & 3);
        lo32[k] = (unsigned)p;
        if (p <= CACHEB - RECENT) candBits |= 1u << k;
    }

    float4 bA[8], bB[8], bC[8], bD[8];
    auto loadrow = [&](int r, float4 (&b)[8]) {
        const float* g = gb + (size_t)r * SEQ;
        #pragma unroll
        for (int i = 0; i < 8; i++) b[i] = *(const float4*)(g + i * 256);
    };
    loadrow(CACHEB + 0, bA);
    loadrow(CACHEB + 1, bB);
    loadrow(CACHEB + 2, bC);
    loadrow(CACHEB + 3, bD);

    auto step = [&](int t, float4 (&cur)[8]) {
        // alive-gating via AND with sign-extended mask bit (identical values:
        // x & ~0 = x, x & 0 = +0.0f) -- no cmp/cndmask, no VCC.
        float m[32];
        float p0 = 0.f, p1 = 0.f, p2 = 0.f, p3 = 0.f;
        #pragma unroll
        for (int i = 0; i < 8; i++) {
            float4 b = cur[i];
            m[i*4+0] = __uint_as_float(__float_as_uint(b.x) & SEXT_BIT(mask, i*4+0));
            m[i*4+1] = __uint_as_float(__float_as_uint(b.y) & SEXT_BIT(mask, i*4+1));
            m[i*4+2] = __uint_as_float(__float_as_uint(b.z) & SEXT_BIT(mask, i*4+2));
            m[i*4+3] = __uint_as_float(__float_as_uint(b.w) & SEXT_BIT(mask, i*4+3));
            p0 += m[i*4+0]; p1 += m[i*4+1]; p2 += m[i*4+2]; p3 += m[i*4+3];
        }
        #pragma unroll
        for (int k = 0; k < 32; k++) sel[k] *= PEN;
        float part = wave_sum64((p0 + p1) + (p2 + p3));
        float inv = 1.f / part;

        // u64 keys: hi = value bits (nonneg floats: u32-monotone), forced to
        // 0xFFFFFFFF for non-candidates/evicted; lo = exact position.
        unsigned ncm = ~(mask & candBits);
        u64 t16[16];
        #pragma unroll
        for (int k = 0; k < 16; k++) {
            float sa = fmaf(m[k],      inv, sel[k]);      sel[k]      = sa;
            float sb = fmaf(m[k + 16], inv, sel[k + 16]); sel[k + 16] = sb;
            unsigned ha = __float_as_uint(sa) | SEXT_BIT(ncm, k);
            unsigned hb = __float_as_uint(sb) | SEXT_BIT(ncm, k + 16);
            u64 ka = ((u64)ha << 32) | lo32[k];
            u64 kb = ((u64)hb << 32) | lo32[k + 16];
            t16[k] = ka < kb ? ka : kb;
        }
        u64 t8[8];
        #pragma unroll
        for (int k = 0; k < 8; k++) t8[k] = t16[k] < t16[k + 8] ? t16[k] : t16[k + 8];
        u64 t4[4];
        #pragma unroll
        for (int k = 0; k < 4; k++) t4[k] = t8[k] < t8[k + 4] ? t8[k] : t8[k + 4];
        u64 t2a = t4[0] < t4[1] ? t4[0] : t4[1];
        u64 t2b = t4[2] < t4[3] ? t4[2] : t4[3];
        u64 lmin = t2a < t2b ? t2a : t2b;
        u64 g = wave_min64_u64(lmin);

        unsigned bpos = (unsigned)g & 0x7ffu;
        int ke = (((int)(bpos >> 8)) << 2) | (int)(bpos & 3);
        if ((((int)bpos >> 2) & 63) == l) mask &= ~(1u << ke);
        if (l == 0) et[bpos] = t;

        int newc = t + 1 - RECENT;
        if (((newc >> 2) & 63) == l) candBits |= 1u << (((newc >> 8) << 2) | (newc & 3));
    };

    int t = CACHEB;
    // main loop: process t..t+3 from bA..bD, prefetch t+4..t+7 (row 2047 is
    // in-bounds and merely unused)
    for (; t + 7 <= SEQ - 1; t += 4) {
        step(t + 0, bA); loadrow(t + 4, bA);
        step(t + 1, bB); loadrow(t + 5, bB);
        step(t + 2, bC); loadrow(t + 6, bC);
        step(t + 3, bD); loadrow(t + 7, bD);
    }
    // tail (t = 2044, 2045, 2046 for SEQ=2048/CACHEB=408)
    if (t <= SEQ - 2) { step(t, bA); t++; }
    if (t <= SEQ - 2) { step(t, bB); t++; }
    if (t <= SEQ - 2) { step(t, bC); t++; }

    #pragma unroll
    for (int s = 0; s < SEQ / 64; s++)
        evict[h * SEQ + s * 64 + l] = et[s * 64 + l];
}

// ---------------- apply mask + renormalize rows >= CACHEB in place --------
__global__ __launch_bounds__(256)
void mask_renorm(float* __restrict__ Sc, const int* __restrict__ evict)
{
    int r = CACHEB + blockIdx.x;
    int h = blockIdx.y;
    float* row = Sc + ((size_t)h * SEQ + r) * SEQ;
    const int* et = evict + h * SEQ;
    int tid = threadIdx.x;
    __shared__ float red[256];
    float v[8]; float sum = 0.f;
    #pragma unroll
    for (int s = 0; s < 8; s++) {
        int c = s * 256 + tid;
        float x = row[c];
        v[s] = (et[c] >= r) ? x : 0.f;
        sum += v[s];
    }
    red[tid] = sum; __syncthreads();
    for (int s = 128; s; s >>= 1) { if (tid < s) red[tid] += red[tid + s]; __syncthreads(); }
    float inv = 1.f / red[0];
    #pragma unroll
    for (int s = 0; s < 8; s++) row[s * 256 + tid] = v[s] * inv;
}

extern "C" void kernel_launch(void* const* d_in, const int* in_sizes, int n_in,
                              void* d_out, int out_size, void* d_ws, size_t ws_size,
                              hipStream_t stream)
{
    const float* hidden = (const float*)d_in[0];
    const int*   pos    = (const int*)d_in[2];
    const float* wq     = (const float*)d_in[3];
    const float* wk     = (const float*)d_in[4];
    const float* wv     = (const float*)d_in[5];
    const float* wo     = (const float*)d_in[6];
    float* out = (float*)d_out;

    float* ws = (float*)d_ws;
    const size_t SD = (size_t)SEQ * DIM;           // 4M elems
    float* Q    = ws;                              // f32, 16 MB
    float* K    = ws + SD;                         // f32, 16 MB
    float* V    = ws + 2 * SD;                     // f32; becomes O after transpose
    float* O    = V;
    u16*   Vth  = (u16*)(ws + 3 * SD);             // bf16-hi Vt (8 MB)
    u16*   Vtl  = Vth + SD;                        // bf16-lo Vt (8 MB)
    float* sel0 = ws + 4 * SD;                     // NH*SEQ floats
    int*   evct = (int*)(ws + 4 * SD + (size_t)NH * SEQ);
    float* Sc   = ws + 4 * SD + 2 * (size_t)NH * SEQ;   // g * SEQ*SEQ floats

    // staging (hi/lo splits) in the not-yet-used Sc region: 4 arrays x SD u16
    u16* hh = (u16*)Sc;        // hidden hi
    u16* hl = hh + SD;         // hidden lo
    u16* wh = hl + SD;         // current weight hi (reused per weight)
    u16* wl = wh + SD;         // current weight lo

    const size_t fixedB   = (4 * SD + 2 * (size_t)NH * SEQ) * sizeof(float);
    const size_t perHeadB = (size_t)SEQ * SEQ * sizeof(float);
    int g = NH;
    while (g > 1 && fixedB + (size_t)g * perHeadB > ws_size) g >>= 1;

    const int N4 = (int)(SD / 4);
    const int CB = (N4 + 255) / 256;

    // 0-1. split + projections (weights staged sequentially)
    split_kernel<<<CB, 256, 0, stream>>>(hidden, hh, hl, N4);
    split_kernel<<<CB, 256, 0, stream>>>(wq, wh, wl, N4);
    mfma_nt<false,false,false,false><<<dim3(16,16,1), 256, 0, stream>>>(
        hh, hl, wh, wl, Q, DIM, DIM, DIM, DIM, 0, 0, 0, 1.f);
    split_kernel<<<CB, 256, 0, stream>>>(wk, wh, wl, N4);
    mfma_nt<false,false,false,false><<<dim3(16,16,1), 256, 0, stream>>>(
        hh, hl, wh, wl, K, DIM, DIM, DIM, DIM, 0, 0, 0, 1.f);
    split_kernel<<<CB, 256, 0, stream>>>(wv, wh, wl, N4);
    mfma_nt<false,false,false,false><<<dim3(16,16,1), 256, 0, stream>>>(
        hh, hl, wh, wl, V, DIM, DIM, DIM, DIM, 0, 0, 0, 1.f);

    // 2. RoPE on Q, K (f32, in place)
    rope_qk<<<dim3(SEQ, NH / 4), 256, 0, stream>>>(Q, K, pos);

    // 3. V -> Vt hi/lo (V storage then becomes O)
    transpose_v<<<dim3(SEQ / 32, HD / 32, NH), dim3(32, 32), 0, stream>>>(V, Vth, Vtl);

    // 4-8 per head-group
    for (int h0 = 0; h0 < NH; h0 += g) {
        int gc = min(g, NH - h0);
        // QK logits: f32 Q,K split in-register, causal tiles, f32 out
        mfma_nt<true,true,true,false><<<dim3(16,16,gc), 256, 0, stream>>>(
            Q + (size_t)h0 * HD, nullptr, K + (size_t)h0 * HD, nullptr, Sc, HD,
            DIM, DIM, SEQ, HD, HD, (long)SEQ * SEQ, QK_SCALE);
        softmax_rows<<<dim3(SEQ, gc), 256, 0, stream>>>(Sc);
        warmup_select<<<dim3(SEQ / 256, gc), 256, 0, stream>>>(Sc, sel0);
        h2o_scan6<<<dim3(gc), 64, 0, stream>>>(Sc, sel0, evct);
        mask_renorm<<<dim3(SEQ - CACHEB, gc), 256, 0, stream>>>(Sc, evct);
        // PV: probs f32 split in-register (K-truncated), Vt pre-split, f32 out
        mfma_nt<true,false,false,true><<<dim3(1,16,gc), 256, 0, stream>>>(
            Sc, nullptr, Vth + (size_t)h0 * HD * SEQ, Vtl + (size_t)h0 * HD * SEQ,
            O + (size_t)h0 * HD, SEQ, SEQ, SEQ, DIM,
            (long)SEQ * SEQ, (long)HD * SEQ, HD, 1.f);
    }

    // 9. final projection: out = O @ wo^T (O split in-register, wo pre-split)
    split_kernel<<<CB, 256, 0, stream>>>(wo, wh, wl, N4);
    mfma_nt<true,false,false,false><<<dim3(16,16,1), 256, 0, stream>>>(
        O, nullptr, wh, wl, out, DIM, DIM, DIM, DIM, 0, 0, 0, 1.f);
}

// Round 5
// 4268.095 us; speedup vs baseline: 1.2126x; 1.0605x over previous
//
#include <hip/hip_runtime.h>
#include <math.h>

#define SEQ 2048
#define DIM 2048
#define NH 16
#define HD 128
#define CACHEB 408
#define RECENT 204
#define PEN 0.4f
#define QK_SCALE 0.08838834764831845f  // 1/sqrt(128)
#define BIGT 0x7fffffff

typedef unsigned short u16;
typedef unsigned long long u64;
typedef __attribute__((ext_vector_type(8))) short bh8;   // 8 bf16 (4 VGPRs)
typedef __attribute__((ext_vector_type(4))) float f32x4; // MFMA acc

__device__ __forceinline__ u16 f2bf(float x) {           // RNE f32->bf16
    unsigned u = __float_as_uint(x);
    return (u16)((u + 0x7fffu + ((u >> 16) & 1u)) >> 16);
}
__device__ __forceinline__ void splitf(float x, u16& h, u16& l) {
    h = f2bf(x);
    float hf = __uint_as_float(((unsigned)h) << 16);
    l = f2bf(x - hf);
}

// ---------------- f32 -> (hi,lo) bf16 split, 4 elems/thread ---------------
__global__ __launch_bounds__(256)
void split_kernel(const float* __restrict__ src, u16* __restrict__ dh,
                  u16* __restrict__ dl, int n4)
{
    int i = blockIdx.x * 256 + threadIdx.x;
    if (i >= n4) return;
    float4 v = ((const float4*)src)[i];
    union { u16 s[4]; unsigned long long q; } oh, ol;
    splitf(v.x, oh.s[0], ol.s[0]); splitf(v.y, oh.s[1], ol.s[1]);
    splitf(v.z, oh.s[2], ol.s[2]); splitf(v.w, oh.s[3], ol.s[3]);
    ((unsigned long long*)dh)[i] = oh.q;
    ((unsigned long long*)dl)[i] = ol.q;
}

// ---------------- split-bf16 MFMA NT GEMM (direct-from-global) ------------
// Kept for QK (K=128) and PV (TRUNCA) paths.
template<bool ASPLITF32, bool BSPLITF32, bool CAUSAL, bool TRUNCA>
__global__ __launch_bounds__(256, 2)
void mfma_nt(const void* __restrict__ Ah_, const void* __restrict__ Al_,
             const void* __restrict__ Bh_, const void* __restrict__ Bl_,
             float* __restrict__ Cp, int K, int lda, int ldb, int ldc,
             long aB, long bB, long cB, float scale)
{
    int m0 = blockIdx.y * 128, n0 = blockIdx.x * 128;
    if (CAUSAL && n0 > m0 + 127) return;

    const float* Af = (const float*)Ah_ + (size_t)blockIdx.z * aB;
    const u16*   Ah = (const u16*)Ah_   + (size_t)blockIdx.z * aB;
    const u16*   Al = (const u16*)Al_   + (size_t)blockIdx.z * aB;
    const float* Bf = (const float*)Bh_ + (size_t)blockIdx.z * bB;
    const u16*   Bh = (const u16*)Bh_   + (size_t)blockIdx.z * bB;
    const u16*   Bl = (const u16*)Bl_   + (size_t)blockIdx.z * bB;
    float* C = Cp + (size_t)blockIdx.z * cB;

    int lane = threadIdx.x & 63, wave = threadIdx.x >> 6;
    int wm = m0 + (wave >> 1) * 64, wn = n0 + (wave & 1) * 64;
    int fr = lane & 15, quad = lane >> 4;
    int kq = quad * 8;

    auto loadA = [&](int mt, int k, bh8& h, bh8& l) {
        int r = wm + mt * 16 + fr;
        if (ASPLITF32) {
            const float* p = Af + (size_t)r * lda + k + kq;
            float4 x = *(const float4*)p, y = *(const float4*)(p + 4);
            u16 hh, ll;
            splitf(x.x,hh,ll); h[0]=(short)hh; l[0]=(short)ll;
            splitf(x.y,hh,ll); h[1]=(short)hh; l[1]=(short)ll;
            splitf(x.z,hh,ll); h[2]=(short)hh; l[2]=(short)ll;
            splitf(x.w,hh,ll); h[3]=(short)hh; l[3]=(short)ll;
            splitf(y.x,hh,ll); h[4]=(short)hh; l[4]=(short)ll;
            splitf(y.y,hh,ll); h[5]=(short)hh; l[5]=(short)ll;
            splitf(y.z,hh,ll); h[6]=(short)hh; l[6]=(short)ll;
            splitf(y.w,hh,ll); h[7]=(short)hh; l[7]=(short)ll;
        } else {
            h = *(const bh8*)(Ah + (size_t)r * lda + k + kq);
            l = *(const bh8*)(Al + (size_t)r * lda + k + kq);
        }
    };
    auto loadB = [&](int nt, int k, bh8& h, bh8& l) {
        int r = wn + nt * 16 + fr;
        if (BSPLITF32) {
            const float* p = Bf + (size_t)r * ldb + k + kq;
            float4 x = *(const float4*)p, y = *(const float4*)(p + 4);
            u16 hh, ll;
            splitf(x.x,hh,ll); h[0]=(short)hh; l[0]=(short)ll;
            splitf(x.y,hh,ll); h[1]=(short)hh; l[1]=(short)ll;
            splitf(x.z,hh,ll); h[2]=(short)hh; l[2]=(short)ll;
            splitf(x.w,hh,ll); h[3]=(short)hh; l[3]=(short)ll;
            splitf(y.x,hh,ll); h[4]=(short)hh; l[4]=(short)ll;
            splitf(y.y,hh,ll); h[5]=(short)hh; l[5]=(short)ll;
            splitf(y.z,hh,ll); h[6]=(short)hh; l[6]=(short)ll;
            splitf(y.w,hh,ll); h[7]=(short)hh; l[7]=(short)ll;
        } else {
            h = *(const bh8*)(Bh + (size_t)r * ldb + k + kq);
            l = *(const bh8*)(Bl + (size_t)r * ldb + k + kq);
        }
    };

    f32x4 acc[4][4] = {};
    int Keff = TRUNCA ? min(K, m0 + 128) : K;

    for (int k0 = 0; k0 < Keff; k0 += 32) {
        bh8 ah[4], al[4], bh[4], bl[4];
        #pragma unroll
        for (int i = 0; i < 4; i++) { loadA(i, k0, ah[i], al[i]); loadB(i, k0, bh[i], bl[i]); }
        #pragma unroll
        for (int mt = 0; mt < 4; mt++)
            #pragma unroll
            for (int nt = 0; nt < 4; nt++) {
                acc[mt][nt] = __builtin_amdgcn_mfma_f32_16x16x32_bf16(ah[mt], bh[nt], acc[mt][nt], 0, 0, 0);
                acc[mt][nt] = __builtin_amdgcn_mfma_f32_16x16x32_bf16(ah[mt], bl[nt], acc[mt][nt], 0, 0, 0);
                acc[mt][nt] = __builtin_amdgcn_mfma_f32_16x16x32_bf16(al[mt], bh[nt], acc[mt][nt], 0, 0, 0);
            }
    }

    #pragma unroll
    for (int mt = 0; mt < 4; mt++)
        #pragma unroll
        for (int r = 0; r < 4; r++) {
            int row = wm + mt * 16 + quad * 4 + r;
            #pragma unroll
            for (int nt = 0; nt < 4; nt++) {
                int col = wn + nt * 16 + fr;
                C[(size_t)row * ldc + col] = acc[mt][nt][r] * scale;
            }
        }
}

// ---------------- split-bf16 MFMA NT GEMM, LDS-staged (2048^3 only) -------
// Same math/accumulation order as mfma_nt<false,false,false,false> ->
// bit-exact results; only the data path changed: global_load_lds width-16
// stages 128x32 tiles of Ah/Al/Bh/Bl into linear LDS (64B rows: b128
// fragment reads are bank-uniform), 2-phase double buffer (issue next-tile
// DMA -> compute current -> one barrier).
__global__ __launch_bounds__(256, 2)
void gemm_nt_staged(const u16* __restrict__ Ah, const u16* __restrict__ Al,
                    const u16* __restrict__ Bh, const u16* __restrict__ Bl,
                    float* __restrict__ C, float scale)
{
    __shared__ u16 sm[2][4][128 * 32];   // [buf][Ah,Al,Bh,Bl][row*32+col], 64 KB

    int m0 = blockIdx.y * 128, n0 = blockIdx.x * 128;
    int tid = threadIdx.x;
    int lane = tid & 63, wave = tid >> 6;
    int fr = lane & 15, quad = lane >> 4;
    int wmr = (wave >> 1) * 64;          // wave's A-row base within tile
    int wnr = (wave & 1) * 64;           // wave's B-row base within tile

    // stage one 128x32 u16 tile per array: 512 16B-chunks, chunk c ->
    // row c>>2, col-chunk c&3. Wave w, half hf covers chunks hf*256+w*64+lane;
    // LDS dest is wave-uniform base + lane*16 (global_load_lds semantics).
    auto stage = [&](int buf, int k0) {
        #pragma unroll
        for (int a = 0; a < 4; a++) {
            const u16* g = (a == 0) ? Ah : (a == 1) ? Al : (a == 2) ? Bh : Bl;
            int r0 = (a < 2) ? m0 : n0;
            #pragma unroll
            for (int hf = 0; hf < 2; hf++) {
                int c = hf * 256 + wave * 64 + lane;
                const u16* src = g + (size_t)(r0 + (c >> 2)) * DIM + k0 + (c & 3) * 8;
                u16* dst = &sm[buf][a][(hf * 256 + wave * 64) * 8];
                __builtin_amdgcn_global_load_lds(
                    (const __attribute__((address_space(1))) void*)src,
                    (__attribute__((address_space(3))) void*)dst, 16, 0, 0);
            }
        }
    };

    f32x4 acc[4][4] = {};

    auto cmpt = [&](int buf) {
        bh8 ah[4], al[4], bhf[4], blf[4];
        #pragma unroll
        for (int i = 0; i < 4; i++) {
            int ra = (wmr + i * 16 + fr) * 32 + quad * 8;
            int rb = (wnr + i * 16 + fr) * 32 + quad * 8;
            ah[i]  = *(const bh8*)&sm[buf][0][ra];
            al[i]  = *(const bh8*)&sm[buf][1][ra];
            bhf[i] = *(const bh8*)&sm[buf][2][rb];
            blf[i] = *(const bh8*)&sm[buf][3][rb];
        }
        #pragma unroll
        for (int mt = 0; mt < 4; mt++)
            #pragma unroll
            for (int nt = 0; nt < 4; nt++) {
                acc[mt][nt] = __builtin_amdgcn_mfma_f32_16x16x32_bf16(ah[mt], bhf[nt], acc[mt][nt], 0, 0, 0);
                acc[mt][nt] = __builtin_amdgcn_mfma_f32_16x16x32_bf16(ah[mt], blf[nt], acc[mt][nt], 0, 0, 0);
                acc[mt][nt] = __builtin_amdgcn_mfma_f32_16x16x32_bf16(al[mt], bhf[nt], acc[mt][nt], 0, 0, 0);
            }
    };

    stage(0, 0);
    __syncthreads();
    int cur = 0;
    for (int k0 = 0; k0 < DIM; k0 += 32) {
        if (k0 + 32 < DIM) stage(cur ^ 1, k0 + 32);  // DMA overlaps compute
        cmpt(cur);
        __syncthreads();                             // drains DMA + publishes
        cur ^= 1;
    }

    int wm = m0 + wmr, wn = n0 + wnr;
    #pragma unroll
    for (int mt = 0; mt < 4; mt++)
        #pragma unroll
        for (int r = 0; r < 4; r++) {
            int row = wm + mt * 16 + quad * 4 + r;
            #pragma unroll
            for (int nt = 0; nt < 4; nt++) {
                int col = wn + nt * 16 + fr;
                C[(size_t)row * DIM + col] = acc[mt][nt][r] * scale;
            }
        }
}

// ---------------- RoPE in place on Q and K (f32) ---------------------------
__global__ __launch_bounds__(256)
void rope_qk(float* __restrict__ Q, float* __restrict__ K, const int* __restrict__ pos_ids)
{
    int s = blockIdx.x;
    int i = threadIdx.x & 63;
    int h = blockIdx.y * 4 + (threadIdx.x >> 6);
    double p = (double)pos_ids[s];
    double invf = exp(-((double)(2 * i) / (double)HD) * 9.210340371976184); // ln(10000)
    double ang = p * invf;
    float c = (float)cos(ang), sn = (float)sin(ang);
    size_t b = (size_t)s * DIM + (size_t)h * HD;
    float q0 = Q[b + i], q1 = Q[b + i + 64];
    Q[b + i]      = q0 * c - q1 * sn;
    Q[b + i + 64] = q1 * c + q0 * sn;
    float k0 = K[b + i], k1 = K[b + i + 64];
    K[b + i]      = k0 * c - k1 * sn;
    K[b + i + 64] = k1 * c + k0 * sn;
}

// ---------------- V(f32) -> Vt hi/lo bf16 [h][hd][s] -----------------------
__global__ __launch_bounds__(1024)
void transpose_v(const float* __restrict__ V, u16* __restrict__ Vth, u16* __restrict__ Vtl)
{
    __shared__ float tile[32][33];
    int h = blockIdx.z;
    int j0 = blockIdx.x * 32, d0 = blockIdx.y * 32;
    int tx = threadIdx.x, ty = threadIdx.y;
    tile[ty][tx] = V[(size_t)(j0 + ty) * DIM + (size_t)h * HD + d0 + tx];
    __syncthreads();
    u16 hh, ll; splitf(tile[tx][ty], hh, ll);
    size_t idx = (size_t)h * HD * SEQ + (size_t)(d0 + ty) * SEQ + j0 + tx;
    Vth[idx] = hh; Vtl[idx] = ll;
}

// ---------------- row softmax (causal) in place on Sc ---------------------
__global__ __launch_bounds__(256)
void softmax_rows(float* __restrict__ Sc)
{
    int r = blockIdx.x, h = blockIdx.y;
    float* row = Sc + ((size_t)h * SEQ + r) * SEQ;
    int n = r + 1;
    __shared__ float red[256];
    int tid = threadIdx.x;
    float mx = -INFINITY;
    for (int j = tid; j < n; j += 256) mx = fmaxf(mx, row[j]);
    red[tid] = mx; __syncthreads();
    for (int s = 128; s; s >>= 1) { if (tid < s) red[tid] = fmaxf(red[tid], red[tid + s]); __syncthreads(); }
    mx = red[0]; __syncthreads();
    float sum = 0.f;
    for (int j = tid; j < n; j += 256) { float e = expf(row[j] - mx); row[j] = e; sum += e; }
    red[tid] = sum; __syncthreads();
    for (int s = 128; s; s >>= 1) { if (tid < s) red[tid] += red[tid + s]; __syncthreads(); }
    float inv = 1.f / red[0];
    for (int j = tid; j < n; j += 256) row[j] *= inv;
    for (int j = n + tid; j < SEQ; j += 256) row[j] = 0.f;
}

// ---------------- parallel warmup: select0[h][c] = sum_t PEN^(407-t)*Sc[t][c]
__global__ __launch_bounds__(256)
void warmup_select(const float* __restrict__ Sc, float* __restrict__ sel0)
{
    int h = blockIdx.y;
    int col = blockIdx.x * 256 + threadIdx.x;
    const float* S = Sc + (size_t)h * SEQ * SEQ + col;
    float s = 0.f;
    #pragma unroll 4
    for (int t = 0; t < CACHEB; t++) s = PEN * s + S[(size_t)t * SEQ];
    sel0[h * SEQ + col] = s;
}

// ---------------- DPP cross-lane helpers ----------------------------------
#define DPP_SUMSTEP(x, ctrl) \
    x += __int_as_float(__builtin_amdgcn_update_dpp(0, __float_as_int(x), ctrl, 0xF, 0xF, true))
#define DPP_SUMBC(x, ctrl) \
    x += __int_as_float(__builtin_amdgcn_update_dpp(0, __float_as_int(x), ctrl, 0xF, 0xF, false))

__device__ __forceinline__ float wave_sum64(float x) {
    DPP_SUMSTEP(x, 0x111); DPP_SUMSTEP(x, 0x112);
    DPP_SUMSTEP(x, 0x114); DPP_SUMSTEP(x, 0x118);
    DPP_SUMBC(x, 0x142);   DPP_SUMBC(x, 0x143);
    return __int_as_float(__builtin_amdgcn_readlane(__float_as_int(x), 63));
}

// 64-bit (value,pos) key min-reduction across the wave.
#define DPP_MIN_U64(x, ctrl) do { \
    unsigned lo_ = (unsigned)(x), hi_ = (unsigned)((x) >> 32); \
    unsigned nlo_ = (unsigned)__builtin_amdgcn_update_dpp((int)lo_, (int)lo_, ctrl, 0xF, 0xF, false); \
    unsigned nhi_ = (unsigned)__builtin_amdgcn_update_dpp((int)hi_, (int)hi_, ctrl, 0xF, 0xF, false); \
    u64 o_ = ((u64)nhi_ << 32) | nlo_; \
    if (o_ < (x)) (x) = o_; \
} while (0)

__device__ __forceinline__ u64 wave_min64_u64(u64 x) {
    DPP_MIN_U64(x, 0x111); DPP_MIN_U64(x, 0x112);
    DPP_MIN_U64(x, 0x114); DPP_MIN_U64(x, 0x118);
    DPP_MIN_U64(x, 0x142); DPP_MIN_U64(x, 0x143);
    unsigned rlo = (unsigned)__builtin_amdgcn_readlane((int)(unsigned)x, 63);
    unsigned rhi = (unsigned)__builtin_amdgcn_readlane((int)(unsigned)(x >> 32), 63);
    return ((u64)rhi << 32) | rlo;
}

// sign-extend bit k of msk to all 32 bits (0 or 0xFFFFFFFF)
#define SEXT_BIT(msk, k) ((unsigned)(((int)((msk) << (31 - (k)))) >> 31))

// ---------------- H2O scan: single wave, register prefetch, u64-key argmin -
// (verified Round-3 version, unchanged)
__global__ __launch_bounds__(64, 1)
void h2o_scan6(const float* __restrict__ Sc, const float* __restrict__ sel0,
               int* __restrict__ evict)
{
    __shared__ int et[SEQ];               // 8 KB

    int h = blockIdx.x;
    int l = threadIdx.x;                  // 0..63, one wave
    const float* Sh = Sc + (size_t)h * SEQ * SEQ;
    const float* gb = Sh + (l << 2);

    #pragma unroll
    for (int s = 0; s < SEQ / 64; s++) et[s * 64 + l] = BIGT;

    float sel[32];
    const float* s0 = sel0 + h * SEQ + l * 4;
    #pragma unroll
    for (int i = 0; i < 8; i++) {
        float4 v = *(const float4*)(s0 + i * 256);
        sel[i*4+0]=v.x; sel[i*4+1]=v.y; sel[i*4+2]=v.z; sel[i*4+3]=v.w;
    }

    unsigned mask = 0xffffffffu;
    unsigned candBits = 0;
    unsigned lo32[32];                    // exact position of (k, lane)
    #pragma unroll
    for (int k = 0; k < 32; k++) {
        int p = ((k >> 2) << 8) + l * 4 + (k & 3);
        lo32[k] = (unsigned)p;
        if (p <= CACHEB - RECENT) candBits |= 1u << k;
    }

    float4 bA[8], bB[8], bC[8], bD[8];
    auto loadrow = [&](int r, float4 (&b)[8]) {
        const float* g = gb + (size_t)r * SEQ;
        #pragma unroll
        for (int i = 0; i < 8; i++) b[i] = *(const float4*)(g + i * 256);
    };
    loadrow(CACHEB + 0, bA);
    loadrow(CACHEB + 1, bB);
    loadrow(CACHEB + 2, bC);
    loadrow(CACHEB + 3, bD);

    auto step = [&](int t, float4 (&cur)[8]) {
        float m[32];
        float p0 = 0.f, p1 = 0.f, p2 = 0.f, p3 = 0.f;
        #pragma unroll
        for (int i = 0; i < 8; i++) {
            float4 b = cur[i];
            m[i*4+0] = __uint_as_float(__float_as_uint(b.x) & SEXT_BIT(mask, i*4+0));
            m[i*4+1] = __uint_as_float(__float_as_uint(b.y) & SEXT_BIT(mask, i*4+1));
            m[i*4+2] = __uint_as_float(__float_as_uint(b.z) & SEXT_BIT(mask, i*4+2));
            m[i*4+3] = __uint_as_float(__float_as_uint(b.w) & SEXT_BIT(mask, i*4+3));
            p0 += m[i*4+0]; p1 += m[i*4+1]; p2 += m[i*4+2]; p3 += m[i*4+3];
        }
        #pragma unroll
        for (int k = 0; k < 32; k++) sel[k] *= PEN;
        float part = wave_sum64((p0 + p1) + (p2 + p3));
        float inv = 1.f / part;

        unsigned ncm = ~(mask & candBits);
        u64 t16[16];
        #pragma unroll
        for (int k = 0; k < 16; k++) {
            float sa = fmaf(m[k],      inv, sel[k]);      sel[k]      = sa;
            float sb = fmaf(m[k + 16], inv, sel[k + 16]); sel[k + 16] = sb;
            unsigned ha = __float_as_uint(sa) | SEXT_BIT(ncm, k);
            unsigned hb = __float_as_uint(sb) | SEXT_BIT(ncm, k + 16);
            u64 ka = ((u64)ha << 32) | lo32[k];
            u64 kb = ((u64)hb << 32) | lo32[k + 16];
            t16[k] = ka < kb ? ka : kb;
        }
        u64 t8[8];
        #pragma unroll
        for (int k = 0; k < 8; k++) t8[k] = t16[k] < t16[k + 8] ? t16[k] : t16[k + 8];
        u64 t4[4];
        #pragma unroll
        for (int k = 0; k < 4; k++) t4[k] = t8[k] < t8[k + 4] ? t8[k] : t8[k + 4];
        u64 t2a = t4[0] < t4[1] ? t4[0] : t4[1];
        u64 t2b = t4[2] < t4[3] ? t4[2] : t4[3];
        u64 lmin = t2a < t2b ? t2a : t2b;
        u64 g = wave_min64_u64(lmin);

        unsigned bpos = (unsigned)g & 0x7ffu;
        int ke = (((int)(bpos >> 8)) << 2) | (int)(bpos & 3);
        if ((((int)bpos >> 2) & 63) == l) mask &= ~(1u << ke);
        if (l == 0) et[bpos] = t;

        int newc = t + 1 - RECENT;
        if (((newc >> 2) & 63) == l) candBits |= 1u << (((newc >> 8) << 2) | (newc & 3));
    };

    int t = CACHEB;
    for (; t + 7 <= SEQ - 1; t += 4) {
        step(t + 0, bA); loadrow(t + 4, bA);
        step(t + 1, bB); loadrow(t + 5, bB);
        step(t + 2, bC); loadrow(t + 6, bC);
        step(t + 3, bD); loadrow(t + 7, bD);
    }
    if (t <= SEQ - 2) { step(t, bA); t++; }
    if (t <= SEQ - 2) { step(t, bB); t++; }
    if (t <= SEQ - 2) { step(t, bC); t++; }

    #pragma unroll
    for (int s = 0; s < SEQ / 64; s++)
        evict[h * SEQ + s * 64 + l] = et[s * 64 + l];
}

// ---------------- apply mask + renormalize rows >= CACHEB in place --------
__global__ __launch_bounds__(256)
void mask_renorm(float* __restrict__ Sc, const int* __restrict__ evict)
{
    int r = CACHEB + blockIdx.x;
    int h = blockIdx.y;
    float* row = Sc + ((size_t)h * SEQ + r) * SEQ;
    const int* et = evict + h * SEQ;
    int tid = threadIdx.x;
    __shared__ float red[256];
    float v[8]; float sum = 0.f;
    #pragma unroll
    for (int s = 0; s < 8; s++) {
        int c = s * 256 + tid;
        float x = row[c];
        v[s] = (et[c] >= r) ? x : 0.f;
        sum += v[s];
    }
    red[tid] = sum; __syncthreads();
    for (int s = 128; s; s >>= 1) { if (tid < s) red[tid] += red[tid + s]; __syncthreads(); }
    float inv = 1.f / red[0];
    #pragma unroll
    for (int s = 0; s < 8; s++) row[s * 256 + tid] = v[s] * inv;
}

extern "C" void kernel_launch(void* const* d_in, const int* in_sizes, int n_in,
                              void* d_out, int out_size, void* d_ws, size_t ws_size,
                              hipStream_t stream)
{
    const float* hidden = (const float*)d_in[0];
    const int*   pos    = (const int*)d_in[2];
    const float* wq     = (const float*)d_in[3];
    const float* wk     = (const float*)d_in[4];
    const float* wv     = (const float*)d_in[5];
    const float* wo     = (const float*)d_in[6];
    float* out = (float*)d_out;

    float* ws = (float*)d_ws;
    const size_t SD = (size_t)SEQ * DIM;           // 4M elems
    float* Q    = ws;                              // f32, 16 MB
    float* K    = ws + SD;                         // f32, 16 MB
    float* V    = ws + 2 * SD;                     // f32; becomes O after transpose
    float* O    = V;
    u16*   Vth  = (u16*)(ws + 3 * SD);             // bf16-hi Vt (8 MB)
    u16*   Vtl  = Vth + SD;                        // bf16-lo Vt (8 MB)
    float* sel0 = ws + 4 * SD;                     // NH*SEQ floats
    int*   evct = (int*)(ws + 4 * SD + (size_t)NH * SEQ);
    float* Sc   = ws + 4 * SD + 2 * (size_t)NH * SEQ;   // g * SEQ*SEQ floats

    // staging (hi/lo splits) in the not-yet-used Sc region: 4 arrays x SD u16
    u16* hh = (u16*)Sc;        // hidden hi (later: O hi)
    u16* hl = hh + SD;         // hidden lo (later: O lo)
    u16* wh = hl + SD;         // current weight hi (reused per weight)
    u16* wl = wh + SD;         // current weight lo

    const size_t fixedB   = (4 * SD + 2 * (size_t)NH * SEQ) * sizeof(float);
    const size_t perHeadB = (size_t)SEQ * SEQ * sizeof(float);
    int g = NH;
    while (g > 1 && fixedB + (size_t)g * perHeadB > ws_size) g >>= 1;

    const int N4 = (int)(SD / 4);
    const int CB = (N4 + 255) / 256;

    // 0-1. split + projections (weights staged sequentially), LDS-staged GEMM
    split_kernel<<<CB, 256, 0, stream>>>(hidden, hh, hl, N4);
    split_kernel<<<CB, 256, 0, stream>>>(wq, wh, wl, N4);
    gemm_nt_staged<<<dim3(16,16), 256, 0, stream>>>(hh, hl, wh, wl, Q, 1.f);
    split_kernel<<<CB, 256, 0, stream>>>(wk, wh, wl, N4);
    gemm_nt_staged<<<dim3(16,16), 256, 0, stream>>>(hh, hl, wh, wl, K, 1.f);
    split_kernel<<<CB, 256, 0, stream>>>(wv, wh, wl, N4);
    gemm_nt_staged<<<dim3(16,16), 256, 0, stream>>>(hh, hl, wh, wl, V, 1.f);

    // 2. RoPE on Q, K (f32, in place)
    rope_qk<<<dim3(SEQ, NH / 4), 256, 0, stream>>>(Q, K, pos);

    // 3. V -> Vt hi/lo (V storage then becomes O)
    transpose_v<<<dim3(SEQ / 32, HD / 32, NH), dim3(32, 32), 0, stream>>>(V, Vth, Vtl);

    // 4-8 per head-group
    for (int h0 = 0; h0 < NH; h0 += g) {
        int gc = min(g, NH - h0);
        // QK logits: f32 Q,K split in-register, causal tiles, f32 out
        mfma_nt<true,true,true,false><<<dim3(16,16,gc), 256, 0, stream>>>(
            Q + (size_t)h0 * HD, nullptr, K + (size_t)h0 * HD, nullptr, Sc, HD,
            DIM, DIM, SEQ, HD, HD, (long)SEQ * SEQ, QK_SCALE);
        softmax_rows<<<dim3(SEQ, gc), 256, 0, stream>>>(Sc);
        warmup_select<<<dim3(SEQ / 256, gc), 256, 0, stream>>>(Sc, sel0);
        h2o_scan6<<<dim3(gc), 64, 0, stream>>>(Sc, sel0, evct);
        mask_renorm<<<dim3(SEQ - CACHEB, gc), 256, 0, stream>>>(Sc, evct);
        // PV: probs f32 split in-register (K-truncated), Vt pre-split, f32 out
        mfma_nt<true,false,false,true><<<dim3(1,16,gc), 256, 0, stream>>>(
            Sc, nullptr, Vth + (size_t)h0 * HD * SEQ, Vtl + (size_t)h0 * HD * SEQ,
            O + (size_t)h0 * HD, SEQ, SEQ, SEQ, DIM,
            (long)SEQ * SEQ, (long)HD * SEQ, HD, 1.f);
    }

    // 9. final projection via staged path: pre-split O (hidden splits are
    // dead by now; same splitf => bit-identical operands to the old in-reg
    // split), then out = O @ wo^T.
    split_kernel<<<CB, 256, 0, stream>>>(O, hh, hl, N4);
    split_kernel<<<CB, 256, 0, stream>>>(wo, wh, wl, N4);
    gemm_nt_staged<<<dim3(16,16), 256, 0, stream>>>(hh, hl, wh, wl, out, 1.f);
}